// Round 3
// baseline (367.639 us; speedup 1.0000x reference)
//
#include <hip/hip_runtime.h>

#define N_NODES 16384
#define N_EDGES 262144
#define BATCH   256
#define F_OUT   32
#define K_ORD   4
#define NT      8      // nodes per final block

// ---------------- transpose: x (B,N) -> xT (N,B) ----------------
__global__ void transpose_kernel(const float* __restrict__ x, float* __restrict__ xT) {
    __shared__ float tile[32][33];
    int tx = threadIdx.x;          // 0..31
    int ty = threadIdx.y;          // 0..7
    int n0 = blockIdx.x * 32;
    int b0 = blockIdx.y * 32;
#pragma unroll
    for (int j = 0; j < 4; ++j) {
        int b = b0 + ty + j * 8;
        int n = n0 + tx;
        tile[ty + j * 8][tx] = x[(size_t)b * N_NODES + n];
    }
    __syncthreads();
#pragma unroll
    for (int j = 0; j < 4; ++j) {
        int n = n0 + ty + j * 8;
        int b = b0 + tx;
        xT[(size_t)n * BATCH + b] = tile[tx][ty + j * 8];
    }
}

// ---------------- CSR build ----------------
__global__ void hist_kernel(const int* __restrict__ rows, int* __restrict__ count) {
    int e = blockIdx.x * blockDim.x + threadIdx.x;
    if (e < N_EDGES) atomicAdd(&count[rows[e]], 1);
}

// single block of 256 threads; 64 entries per thread
__global__ void scan_kernel(int* __restrict__ count, int* __restrict__ row_ptr) {
    __shared__ int part[256];
    int t = threadIdx.x;
    int base = t * 64;
    int loc[64];
    int s = 0;
#pragma unroll
    for (int i = 0; i < 64; ++i) { loc[i] = count[base + i]; s += loc[i]; }
    part[t] = s;
    __syncthreads();
    for (int d = 1; d < 256; d <<= 1) {
        int v = (t >= d) ? part[t - d] : 0;
        __syncthreads();
        part[t] += v;
        __syncthreads();
    }
    int off = part[t] - s;  // exclusive prefix
#pragma unroll
    for (int i = 0; i < 64; ++i) {
        row_ptr[base + i] = off;
        count[base + i] = off;   // becomes the scatter cursor
        off += loc[i];
    }
    if (t == 255) row_ptr[N_NODES] = off;   // == N_EDGES
}

__global__ void scatter_kernel(const int* __restrict__ rows, const int* __restrict__ cols,
                               const float* __restrict__ vals,
                               int* __restrict__ cursor,
                               int* __restrict__ csr_col, float* __restrict__ csr_val) {
    int e = blockIdx.x * blockDim.x + threadIdx.x;
    if (e < N_EDGES) {
        int r = rows[e];
        int pos = atomicAdd(&cursor[r], 1);
        csr_col[pos] = cols[e];
        csr_val[pos] = vals[e];
    }
}

// ---------------- Chebyshev step: out = c*(L@in - in) - prev ----------------
__global__ void cheb_kernel(const float* __restrict__ in, const float* __restrict__ prev,
                            float* __restrict__ out,
                            const int* __restrict__ row_ptr,
                            const float* __restrict__ csr_val, const int* __restrict__ csr_col,
                            float c) {
    int n = blockIdx.x;
    int tid = threadIdx.x;   // batch lane
    int beg = row_ptr[n], end = row_ptr[n + 1];
    float acc = 0.f;
    int e = beg;
    for (; e + 3 < end; e += 4) {
        int   c0 = csr_col[e],     c1 = csr_col[e + 1], c2 = csr_col[e + 2], c3 = csr_col[e + 3];
        float v0 = csr_val[e],     v1 = csr_val[e + 1], v2 = csr_val[e + 2], v3 = csr_val[e + 3];
        acc += v0 * in[(size_t)c0 * BATCH + tid];
        acc += v1 * in[(size_t)c1 * BATCH + tid];
        acc += v2 * in[(size_t)c2 * BATCH + tid];
        acc += v3 * in[(size_t)c3 * BATCH + tid];
    }
    for (; e < end; ++e)
        acc += csr_val[e] * in[(size_t)csr_col[e] * BATCH + tid];
    size_t idx = (size_t)n * BATCH + tid;
    float o = c * (acc - in[idx]);
    if (prev) o -= prev[idx];
    out[idx] = o;
}

// ---------------- fused: T3 = 2*(L@T2 - T2) - T1 ; y = [T0..T3] @ W^T + b ----------------
// NT=8 nodes per block. Phase 1: per node, 256 threads (b=tid) compute t0..t3, stage in LDS.
// Phase 2: each wave emits out[b][n0..n0+7][0..31] = 1024 contiguous bytes per store instr.
__global__ void final_kernel(const float* __restrict__ t0, const float* __restrict__ t1,
                             const float* __restrict__ t2,
                             const int* __restrict__ row_ptr,
                             const float* __restrict__ csr_val, const int* __restrict__ csr_col,
                             const float* __restrict__ weight, const float* __restrict__ bias,
                             float* __restrict__ out) {
    __shared__ float w[F_OUT * K_ORD];
    __shared__ float bb[F_OUT];
    __shared__ float4 tval[NT][BATCH + 1];   // +1 float4 row pad -> phase-2 reads conflict-free
    int tid = threadIdx.x;
    if (tid < F_OUT * K_ORD) w[tid] = weight[tid];
    if (tid < F_OUT) bb[tid] = bias[tid];

    int n0 = blockIdx.x * NT;
#pragma unroll
    for (int nn = 0; nn < NT; ++nn) {
        int n = n0 + nn;
        int beg = row_ptr[n], end = row_ptr[n + 1];
        float acc = 0.f;
        int e = beg;
        for (; e + 3 < end; e += 4) {
            int   c0 = csr_col[e],     c1 = csr_col[e + 1], c2 = csr_col[e + 2], c3 = csr_col[e + 3];
            float v0 = csr_val[e],     v1 = csr_val[e + 1], v2 = csr_val[e + 2], v3 = csr_val[e + 3];
            acc += v0 * t2[(size_t)c0 * BATCH + tid];
            acc += v1 * t2[(size_t)c1 * BATCH + tid];
            acc += v2 * t2[(size_t)c2 * BATCH + tid];
            acc += v3 * t2[(size_t)c3 * BATCH + tid];
        }
        for (; e < end; ++e)
            acc += csr_val[e] * t2[(size_t)csr_col[e] * BATCH + tid];

        size_t idx = (size_t)n * BATCH + tid;
        float t2v = t2[idx];
        float t3v = 2.f * (acc - t2v) - t1[idx];
        tval[nn][tid] = make_float4(t0[idx], t1[idx], t2v, t3v);
    }
    __syncthreads();

    // phase 2
    int wave = tid >> 6;            // 0..3
    int lane = tid & 63;
    int nsub = lane >> 3;           // 0..7: node within tile
    int f    = (lane & 7) * 4;      // feature start

    // hoist this lane's weights/bias to registers
    float4 w0 = *(const float4*)&w[(f + 0) * 4];
    float4 w1 = *(const float4*)&w[(f + 1) * 4];
    float4 w2 = *(const float4*)&w[(f + 2) * 4];
    float4 w3 = *(const float4*)&w[(f + 3) * 4];
    float4 b4 = *(const float4*)&bb[f];

    const size_t rowStride = (size_t)N_NODES * F_OUT;
    float* obase = out + ((size_t)(n0 + nsub)) * F_OUT + f;
#pragma unroll 4
    for (int i = 0; i < 64; ++i) {
        int b = wave * 64 + i;
        float4 tv = tval[nsub][b];
        float4 r;
        r.x = w0.x * tv.x + w0.y * tv.y + w0.z * tv.z + w0.w * tv.w + b4.x;
        r.y = w1.x * tv.x + w1.y * tv.y + w1.z * tv.z + w1.w * tv.w + b4.y;
        r.z = w2.x * tv.x + w2.y * tv.y + w2.z * tv.z + w2.w * tv.w + b4.z;
        r.w = w3.x * tv.x + w3.y * tv.y + w3.z * tv.z + w3.w * tv.w + b4.w;
        *(float4*)(obase + (size_t)b * rowStride) = r;
    }
}

extern "C" void kernel_launch(void* const* d_in, const int* in_sizes, int n_in,
                              void* d_out, int out_size, void* d_ws, size_t ws_size,
                              hipStream_t stream) {
    const float* x      = (const float*)d_in[0];
    const float* vals   = (const float*)d_in[1];
    const int*   rows   = (const int*)d_in[2];
    const int*   cols   = (const int*)d_in[3];
    const float* weight = (const float*)d_in[4];
    const float* bias   = (const float*)d_in[5];
    float* out = (float*)d_out;

    const size_t NB = (size_t)N_NODES * BATCH;   // 4,194,304 floats
    float* xT      = (float*)d_ws;
    float* t1      = xT + NB;
    float* t2      = t1 + NB;
    int*   row_ptr = (int*)(t2 + NB);            // N_NODES+1 (pad to 16448)
    int*   cursor  = row_ptr + 16448;            // N_NODES ints; also the histogram
    float* csr_val = (float*)(cursor + N_NODES);
    int*   csr_col = (int*)(csr_val + N_EDGES);

    hipMemsetAsync(cursor, 0, N_NODES * sizeof(int), stream);

    transpose_kernel<<<dim3(N_NODES / 32, BATCH / 32), dim3(32, 8), 0, stream>>>(x, xT);
    hist_kernel<<<N_EDGES / 256, 256, 0, stream>>>(rows, cursor);
    scan_kernel<<<1, 256, 0, stream>>>(cursor, row_ptr);
    scatter_kernel<<<N_EDGES / 256, 256, 0, stream>>>(rows, cols, vals, cursor, csr_col, csr_val);

    cheb_kernel<<<N_NODES, 256, 0, stream>>>(xT, nullptr, t1, row_ptr, csr_val, csr_col, 1.f);
    cheb_kernel<<<N_NODES, 256, 0, stream>>>(t1, xT, t2, row_ptr, csr_val, csr_col, 2.f);
    final_kernel<<<N_NODES / NT, 256, 0, stream>>>(xT, t1, t2, row_ptr, csr_val, csr_col,
                                                   weight, bias, out);
}

// Round 5
// 254.195 us; speedup vs baseline: 1.4463x; 1.4463x over previous
//
#include <hip/hip_runtime.h>

#define N_NODES 16384
#define N_EDGES 262144
#define BATCH   256
#define F_OUT   32
#define K_ORD   4

typedef float f32x4 __attribute__((ext_vector_type(4)));

// ---------------- transpose: x (B,N) -> xT (N,B) ----------------
__global__ void transpose_kernel(const float* __restrict__ x, float* __restrict__ xT) {
    __shared__ float tile[32][33];
    int tx = threadIdx.x;          // 0..31
    int ty = threadIdx.y;          // 0..7
    int n0 = blockIdx.x * 32;
    int b0 = blockIdx.y * 32;
#pragma unroll
    for (int j = 0; j < 4; ++j) {
        int b = b0 + ty + j * 8;
        int n = n0 + tx;
        tile[ty + j * 8][tx] = x[(size_t)b * N_NODES + n];
    }
    __syncthreads();
#pragma unroll
    for (int j = 0; j < 4; ++j) {
        int n = n0 + ty + j * 8;
        int b = b0 + tx;
        xT[(size_t)n * BATCH + b] = tile[tx][ty + j * 8];
    }
}

// ---------------- CSR build ----------------
__global__ void hist_kernel(const int* __restrict__ rows, int* __restrict__ count) {
    int e = blockIdx.x * blockDim.x + threadIdx.x;
    if (e < N_EDGES) atomicAdd(&count[rows[e]], 1);
}

__global__ void scan_kernel(int* __restrict__ count, int* __restrict__ row_ptr) {
    __shared__ int part[256];
    int t = threadIdx.x;
    int base = t * 64;
    int loc[64];
    int s = 0;
#pragma unroll
    for (int i = 0; i < 64; ++i) { loc[i] = count[base + i]; s += loc[i]; }
    part[t] = s;
    __syncthreads();
    for (int d = 1; d < 256; d <<= 1) {
        int v = (t >= d) ? part[t - d] : 0;
        __syncthreads();
        part[t] += v;
        __syncthreads();
    }
    int off = part[t] - s;  // exclusive prefix
#pragma unroll
    for (int i = 0; i < 64; ++i) {
        row_ptr[base + i] = off;
        count[base + i] = off;   // becomes the scatter cursor
        off += loc[i];
    }
    if (t == 255) row_ptr[N_NODES] = off;   // == N_EDGES
}

__global__ void scatter_kernel(const int* __restrict__ rows, const int* __restrict__ cols,
                               const float* __restrict__ vals,
                               int* __restrict__ cursor,
                               int* __restrict__ csr_col, float* __restrict__ csr_val) {
    int e = blockIdx.x * blockDim.x + threadIdx.x;
    if (e < N_EDGES) {
        int r = rows[e];
        int pos = atomicAdd(&cursor[r], 1);
        csr_col[pos] = cols[e];
        csr_val[pos] = vals[e];
    }
}

// ---------------- Chebyshev step: out = c*(L@in - in) - prev ----------------
// 4 nodes per block; 64 lanes x float4 cover one full 1KB row per wave instruction.
__global__ void cheb_kernel(const float* __restrict__ in, const float* __restrict__ prev,
                            float* __restrict__ out,
                            const int* __restrict__ row_ptr,
                            const float* __restrict__ csr_val, const int* __restrict__ csr_col,
                            float c) {
    int n = blockIdx.x * 4 + (threadIdx.x >> 6);
    int lane = threadIdx.x & 63;          // covers 4 batch lanes via float4
    int beg = row_ptr[n], end = row_ptr[n + 1];
    f32x4 acc = (f32x4)(0.f);
    int e = beg;
    for (; e + 1 < end; e += 2) {
        int   c0 = csr_col[e],  c1 = csr_col[e + 1];
        float v0 = csr_val[e],  v1 = csr_val[e + 1];
        f32x4 a = *(const f32x4*)&in[(size_t)c0 * BATCH + lane * 4];
        f32x4 b = *(const f32x4*)&in[(size_t)c1 * BATCH + lane * 4];
        acc += v0 * a + v1 * b;
    }
    if (e < end) {
        float v0 = csr_val[e];
        f32x4 a = *(const f32x4*)&in[(size_t)csr_col[e] * BATCH + lane * 4];
        acc += v0 * a;
    }
    size_t idx = (size_t)n * BATCH + lane * 4;
    f32x4 self = *(const f32x4*)&in[idx];
    f32x4 o = c * (acc - self);
    if (prev) {
        f32x4 p = *(const f32x4*)&prev[idx];
        o -= p;
    }
    *(f32x4*)&out[idx] = o;
}

// ---------------- fused: T3 = 2*(L@T2 - T2) - T1 ; y = [T0..T3] @ W^T + b ----------------
// One node per block (high occupancy). Phase 2: line-complete 128B writes, nontemporal
// so the 512MB output stream doesn't evict the gather working set from L2.
__global__ void final_kernel(const float* __restrict__ t0, const float* __restrict__ t1,
                             const float* __restrict__ t2,
                             const int* __restrict__ row_ptr,
                             const float* __restrict__ csr_val, const int* __restrict__ csr_col,
                             const float* __restrict__ weight, const float* __restrict__ bias,
                             float* __restrict__ out) {
    __shared__ float w[F_OUT * K_ORD];
    __shared__ float bb[F_OUT];
    __shared__ float tval[BATCH][4];
    int tid = threadIdx.x;             // phase-1: batch lane b
    if (tid < F_OUT * K_ORD) w[tid] = weight[tid];
    if (tid < F_OUT) bb[tid] = bias[tid];
    __syncthreads();

    int n = blockIdx.x;
    int beg = row_ptr[n], end = row_ptr[n + 1];
    float acc = 0.f;
    int e = beg;
    for (; e + 3 < end; e += 4) {
        int   c0 = csr_col[e],     c1 = csr_col[e + 1], c2 = csr_col[e + 2], c3 = csr_col[e + 3];
        float v0 = csr_val[e],     v1 = csr_val[e + 1], v2 = csr_val[e + 2], v3 = csr_val[e + 3];
        acc += v0 * t2[(size_t)c0 * BATCH + tid];
        acc += v1 * t2[(size_t)c1 * BATCH + tid];
        acc += v2 * t2[(size_t)c2 * BATCH + tid];
        acc += v3 * t2[(size_t)c3 * BATCH + tid];
    }
    for (; e < end; ++e)
        acc += csr_val[e] * t2[(size_t)csr_col[e] * BATCH + tid];

    size_t idx = (size_t)n * BATCH + tid;
    float t2v = t2[idx];
    float t3v = 2.f * (acc - t2v) - t1[idx];
    *(f32x4*)&tval[tid][0] = (f32x4){t0[idx], t1[idx], t2v, t3v};
    __syncthreads();

    // phase 2: 2048 float4 outputs for this node; thread t does 8 of them.
    // f-group is i-invariant -> hoist weights to registers.
    int f = (tid & 7) * 4;
    f32x4 w0 = *(const f32x4*)&w[(f + 0) * 4];
    f32x4 w1 = *(const f32x4*)&w[(f + 1) * 4];
    f32x4 w2 = *(const f32x4*)&w[(f + 2) * 4];
    f32x4 w3 = *(const f32x4*)&w[(f + 3) * 4];
    f32x4 b4 = *(const f32x4*)&bb[f];

    const size_t nF = (size_t)n * F_OUT;
#pragma unroll
    for (int i = 0; i < 8; ++i) {
        int g = i * 256 + tid;         // 0..2047
        int b = g >> 3;                // batch index
        f32x4 tv = *(const f32x4*)&tval[b][0];
        f32x4 r;
        r.x = w0.x * tv.x + w0.y * tv.y + w0.z * tv.z + w0.w * tv.w + b4.x;
        r.y = w1.x * tv.x + w1.y * tv.y + w1.z * tv.z + w1.w * tv.w + b4.y;
        r.z = w2.x * tv.x + w2.y * tv.y + w2.z * tv.z + w2.w * tv.w + b4.z;
        r.w = w3.x * tv.x + w3.y * tv.y + w3.z * tv.z + w3.w * tv.w + b4.w;
        __builtin_nontemporal_store(r, (f32x4*)(out + ((size_t)b * N_NODES) * F_OUT + nF + f));
    }
}

extern "C" void kernel_launch(void* const* d_in, const int* in_sizes, int n_in,
                              void* d_out, int out_size, void* d_ws, size_t ws_size,
                              hipStream_t stream) {
    const float* x      = (const float*)d_in[0];
    const float* vals   = (const float*)d_in[1];
    const int*   rows   = (const int*)d_in[2];
    const int*   cols   = (const int*)d_in[3];
    const float* weight = (const float*)d_in[4];
    const float* bias   = (const float*)d_in[5];
    float* out = (float*)d_out;

    const size_t NB = (size_t)N_NODES * BATCH;   // 4,194,304 floats
    float* xT      = (float*)d_ws;
    float* t1      = xT + NB;
    float* t2      = t1 + NB;
    int*   row_ptr = (int*)(t2 + NB);            // N_NODES+1 (pad to 16448)
    int*   cursor  = row_ptr + 16448;            // N_NODES ints; also the histogram
    float* csr_val = (float*)(cursor + N_NODES);
    int*   csr_col = (int*)(csr_val + N_EDGES);

    (void)hipMemsetAsync(cursor, 0, N_NODES * sizeof(int), stream);

    transpose_kernel<<<dim3(N_NODES / 32, BATCH / 32), dim3(32, 8), 0, stream>>>(x, xT);
    hist_kernel<<<N_EDGES / 256, 256, 0, stream>>>(rows, cursor);
    scan_kernel<<<1, 256, 0, stream>>>(cursor, row_ptr);
    scatter_kernel<<<N_EDGES / 256, 256, 0, stream>>>(rows, cols, vals, cursor, csr_col, csr_val);

    cheb_kernel<<<N_NODES / 4, 256, 0, stream>>>(xT, nullptr, t1, row_ptr, csr_val, csr_col, 1.f);
    cheb_kernel<<<N_NODES / 4, 256, 0, stream>>>(t1, xT, t2, row_ptr, csr_val, csr_col, 2.f);
    final_kernel<<<N_NODES, 256, 0, stream>>>(xT, t1, t2, row_ptr, csr_val, csr_col,
                                              weight, bias, out);
}

// Round 6
// 254.142 us; speedup vs baseline: 1.4466x; 1.0002x over previous
//
#include <hip/hip_runtime.h>

#define N_NODES 16384
#define N_EDGES 262144
#define BATCH   256
#define F_OUT   32
#define K_ORD   4
#define NV      4      // nodes per final block (one wave each)

typedef float f32x4 __attribute__((ext_vector_type(4)));

// ---------------- transpose: x (B,N) -> xT (N,B) ----------------
__global__ void transpose_kernel(const float* __restrict__ x, float* __restrict__ xT) {
    __shared__ float tile[32][33];
    int tx = threadIdx.x;          // 0..31
    int ty = threadIdx.y;          // 0..7
    int n0 = blockIdx.x * 32;
    int b0 = blockIdx.y * 32;
#pragma unroll
    for (int j = 0; j < 4; ++j) {
        int b = b0 + ty + j * 8;
        int n = n0 + tx;
        tile[ty + j * 8][tx] = x[(size_t)b * N_NODES + n];
    }
    __syncthreads();
#pragma unroll
    for (int j = 0; j < 4; ++j) {
        int n = n0 + ty + j * 8;
        int b = b0 + tx;
        xT[(size_t)n * BATCH + b] = tile[tx][ty + j * 8];
    }
}

// ---------------- CSR build ----------------
__global__ void hist_kernel(const int* __restrict__ rows, int* __restrict__ count) {
    int e = blockIdx.x * blockDim.x + threadIdx.x;
    if (e < N_EDGES) atomicAdd(&count[rows[e]], 1);
}

__global__ void scan_kernel(int* __restrict__ count, int* __restrict__ row_ptr) {
    __shared__ int part[256];
    int t = threadIdx.x;
    int base = t * 64;
    int loc[64];
    int s = 0;
#pragma unroll
    for (int i = 0; i < 64; ++i) { loc[i] = count[base + i]; s += loc[i]; }
    part[t] = s;
    __syncthreads();
    for (int d = 1; d < 256; d <<= 1) {
        int v = (t >= d) ? part[t - d] : 0;
        __syncthreads();
        part[t] += v;
        __syncthreads();
    }
    int off = part[t] - s;  // exclusive prefix
#pragma unroll
    for (int i = 0; i < 64; ++i) {
        row_ptr[base + i] = off;
        count[base + i] = off;   // becomes the scatter cursor
        off += loc[i];
    }
    if (t == 255) row_ptr[N_NODES] = off;   // == N_EDGES
}

__global__ void scatter_kernel(const int* __restrict__ rows, const int* __restrict__ cols,
                               const float* __restrict__ vals,
                               int* __restrict__ cursor,
                               int* __restrict__ csr_col, float* __restrict__ csr_val) {
    int e = blockIdx.x * blockDim.x + threadIdx.x;
    if (e < N_EDGES) {
        int r = rows[e];
        int pos = atomicAdd(&cursor[r], 1);
        csr_col[pos] = cols[e];
        csr_val[pos] = vals[e];
    }
}

// ---------------- Chebyshev step: out = c*(L@in - in) - prev ----------------
// 4 nodes per block (one wave each); 64 lanes x f32x4 = full 1KB row per load.
// Unroll 4 edges -> 4 independent row loads in flight (latency hiding).
__global__ void cheb_kernel(const float* __restrict__ in, const float* __restrict__ prev,
                            float* __restrict__ out,
                            const int* __restrict__ row_ptr,
                            const float* __restrict__ csr_val, const int* __restrict__ csr_col,
                            float c) {
    int n = blockIdx.x * 4 + (threadIdx.x >> 6);
    int lane = threadIdx.x & 63;
    int beg = row_ptr[n], end = row_ptr[n + 1];
    f32x4 acc = (f32x4)(0.f);
    int e = beg;
    for (; e + 3 < end; e += 4) {
        int   c0 = csr_col[e],     c1 = csr_col[e + 1], c2 = csr_col[e + 2], c3 = csr_col[e + 3];
        float v0 = csr_val[e],     v1 = csr_val[e + 1], v2 = csr_val[e + 2], v3 = csr_val[e + 3];
        f32x4 a0 = *(const f32x4*)&in[(size_t)c0 * BATCH + lane * 4];
        f32x4 a1 = *(const f32x4*)&in[(size_t)c1 * BATCH + lane * 4];
        f32x4 a2 = *(const f32x4*)&in[(size_t)c2 * BATCH + lane * 4];
        f32x4 a3 = *(const f32x4*)&in[(size_t)c3 * BATCH + lane * 4];
        acc += v0 * a0 + v1 * a1 + v2 * a2 + v3 * a3;
    }
    for (; e < end; ++e) {
        float v0 = csr_val[e];
        f32x4 a = *(const f32x4*)&in[(size_t)csr_col[e] * BATCH + lane * 4];
        acc += v0 * a;
    }
    size_t idx = (size_t)n * BATCH + lane * 4;
    f32x4 self = *(const f32x4*)&in[idx];
    f32x4 o = c * (acc - self);
    if (prev) {
        f32x4 p = *(const f32x4*)&prev[idx];
        o -= p;
    }
    *(f32x4*)&out[idx] = o;
}

// ---------------- fused: T3 = 2*(L@T2 - T2) - T1 ; y = [T0..T3] @ W^T + b ----------------
// NV=4 nodes per block, one wave per node. Phase 1: f32x4 gathers (64 lanes = 1KB row),
// unroll 4. Phase 2: line-complete 128B nontemporal writes; weights amortized over 4 nodes.
__global__ void final_kernel(const float* __restrict__ t0, const float* __restrict__ t1,
                             const float* __restrict__ t2,
                             const int* __restrict__ row_ptr,
                             const float* __restrict__ csr_val, const int* __restrict__ csr_col,
                             const float* __restrict__ weight, const float* __restrict__ bias,
                             float* __restrict__ out) {
    __shared__ float w[F_OUT * K_ORD];
    __shared__ float bb[F_OUT];
    __shared__ f32x4 tval[NV][BATCH];   // [node][b] = {t0,t1,t2,t3}
    int tid = threadIdx.x;
    if (tid < F_OUT * K_ORD) w[tid] = weight[tid];
    if (tid < F_OUT) bb[tid] = bias[tid];

    int n0 = blockIdx.x * NV;
    int wv = tid >> 6;                 // wave = node within block
    int lane = tid & 63;
    {
        int n = n0 + wv;
        int beg = row_ptr[n], end = row_ptr[n + 1];
        f32x4 acc = (f32x4)(0.f);
        int e = beg;
        for (; e + 3 < end; e += 4) {
            int   c0 = csr_col[e],     c1 = csr_col[e + 1], c2 = csr_col[e + 2], c3 = csr_col[e + 3];
            float v0 = csr_val[e],     v1 = csr_val[e + 1], v2 = csr_val[e + 2], v3 = csr_val[e + 3];
            f32x4 a0 = *(const f32x4*)&t2[(size_t)c0 * BATCH + lane * 4];
            f32x4 a1 = *(const f32x4*)&t2[(size_t)c1 * BATCH + lane * 4];
            f32x4 a2 = *(const f32x4*)&t2[(size_t)c2 * BATCH + lane * 4];
            f32x4 a3 = *(const f32x4*)&t2[(size_t)c3 * BATCH + lane * 4];
            acc += v0 * a0 + v1 * a1 + v2 * a2 + v3 * a3;
        }
        for (; e < end; ++e) {
            float v0 = csr_val[e];
            f32x4 a = *(const f32x4*)&t2[(size_t)csr_col[e] * BATCH + lane * 4];
            acc += v0 * a;
        }
        size_t idx = (size_t)n * BATCH + lane * 4;
        f32x4 t0r = *(const f32x4*)&t0[idx];
        f32x4 t1r = *(const f32x4*)&t1[idx];
        f32x4 t2r = *(const f32x4*)&t2[idx];
        f32x4 t3r = 2.f * (acc - t2r) - t1r;
#pragma unroll
        for (int j = 0; j < 4; ++j)
            tval[wv][lane * 4 + j] = (f32x4){t0r[j], t1r[j], t2r[j], t3r[j]};
    }
    __syncthreads();

    // phase 2: per node, 2048 f32x4 outputs; thread does 8 per node.
    int f = (tid & 7) * 4;
    f32x4 w0 = *(const f32x4*)&w[(f + 0) * 4];
    f32x4 w1 = *(const f32x4*)&w[(f + 1) * 4];
    f32x4 w2 = *(const f32x4*)&w[(f + 2) * 4];
    f32x4 w3 = *(const f32x4*)&w[(f + 3) * 4];
    f32x4 b4 = *(const f32x4*)&bb[f];

#pragma unroll
    for (int nn = 0; nn < NV; ++nn) {
        const size_t nF = (size_t)(n0 + nn) * F_OUT;
#pragma unroll
        for (int i = 0; i < 8; ++i) {
            int g = i * 256 + tid;         // 0..2047
            int b = g >> 3;                // batch index
            f32x4 tv = tval[nn][b];
            f32x4 r;
            r.x = w0.x * tv.x + w0.y * tv.y + w0.z * tv.z + w0.w * tv.w + b4.x;
            r.y = w1.x * tv.x + w1.y * tv.y + w1.z * tv.z + w1.w * tv.w + b4.y;
            r.z = w2.x * tv.x + w2.y * tv.y + w2.z * tv.z + w2.w * tv.w + b4.z;
            r.w = w3.x * tv.x + w3.y * tv.y + w3.z * tv.z + w3.w * tv.w + b4.w;
            __builtin_nontemporal_store(r, (f32x4*)(out + ((size_t)b * N_NODES) * F_OUT + nF + f));
        }
    }
}

extern "C" void kernel_launch(void* const* d_in, const int* in_sizes, int n_in,
                              void* d_out, int out_size, void* d_ws, size_t ws_size,
                              hipStream_t stream) {
    const float* x      = (const float*)d_in[0];
    const float* vals   = (const float*)d_in[1];
    const int*   rows   = (const int*)d_in[2];
    const int*   cols   = (const int*)d_in[3];
    const float* weight = (const float*)d_in[4];
    const float* bias   = (const float*)d_in[5];
    float* out = (float*)d_out;

    const size_t NB = (size_t)N_NODES * BATCH;   // 4,194,304 floats
    float* xT      = (float*)d_ws;
    float* t1      = xT + NB;
    float* t2      = t1 + NB;
    int*   row_ptr = (int*)(t2 + NB);            // N_NODES+1 (pad to 16448)
    int*   cursor  = row_ptr + 16448;            // N_NODES ints; also the histogram
    float* csr_val = (float*)(cursor + N_NODES);
    int*   csr_col = (int*)(csr_val + N_EDGES);

    (void)hipMemsetAsync(cursor, 0, N_NODES * sizeof(int), stream);

    transpose_kernel<<<dim3(N_NODES / 32, BATCH / 32), dim3(32, 8), 0, stream>>>(x, xT);
    hist_kernel<<<N_EDGES / 256, 256, 0, stream>>>(rows, cursor);
    scan_kernel<<<1, 256, 0, stream>>>(cursor, row_ptr);
    scatter_kernel<<<N_EDGES / 256, 256, 0, stream>>>(rows, cols, vals, cursor, csr_col, csr_val);

    cheb_kernel<<<N_NODES / 4, 256, 0, stream>>>(xT, nullptr, t1, row_ptr, csr_val, csr_col, 1.f);
    cheb_kernel<<<N_NODES / 4, 256, 0, stream>>>(t1, xT, t2, row_ptr, csr_val, csr_col, 2.f);
    final_kernel<<<N_NODES / NV, 256, 0, stream>>>(xT, t1, t2, row_ptr, csr_val, csr_col,
                                                   weight, bias, out);
}

// Round 7
// 247.661 us; speedup vs baseline: 1.4844x; 1.0262x over previous
//
#include <hip/hip_runtime.h>

#define N_NODES 16384
#define N_EDGES 262144
#define BATCH   256
#define F_OUT   32
#define K_ORD   4
#define NCHUNK  8      // batch chunks == XCD count
#define CHUNK   32     // batch lanes per chunk
#define NPB     8      // nodes per block (cheb & final)

typedef float f32x4 __attribute__((ext_vector_type(4)));

// ---------------- transpose: x (B,N) -> xT (N,B) ----------------
__global__ void transpose_kernel(const float* __restrict__ x, float* __restrict__ xT) {
    __shared__ float tile[32][33];
    int tx = threadIdx.x;          // 0..31
    int ty = threadIdx.y;          // 0..7
    int n0 = blockIdx.x * 32;
    int b0 = blockIdx.y * 32;
#pragma unroll
    for (int j = 0; j < 4; ++j) {
        int b = b0 + ty + j * 8;
        int n = n0 + tx;
        tile[ty + j * 8][tx] = x[(size_t)b * N_NODES + n];
    }
    __syncthreads();
#pragma unroll
    for (int j = 0; j < 4; ++j) {
        int n = n0 + ty + j * 8;
        int b = b0 + tx;
        xT[(size_t)n * BATCH + b] = tile[tx][ty + j * 8];
    }
}

// ---------------- CSR build ----------------
__global__ void hist_kernel(const int* __restrict__ rows, int* __restrict__ count) {
    int e = blockIdx.x * blockDim.x + threadIdx.x;
    if (e < N_EDGES) atomicAdd(&count[rows[e]], 1);
}

__global__ void scan_kernel(int* __restrict__ count, int* __restrict__ row_ptr) {
    __shared__ int part[256];
    int t = threadIdx.x;
    int base = t * 64;
    int loc[64];
    int s = 0;
#pragma unroll
    for (int i = 0; i < 64; ++i) { loc[i] = count[base + i]; s += loc[i]; }
    part[t] = s;
    __syncthreads();
    for (int d = 1; d < 256; d <<= 1) {
        int v = (t >= d) ? part[t - d] : 0;
        __syncthreads();
        part[t] += v;
        __syncthreads();
    }
    int off = part[t] - s;  // exclusive prefix
#pragma unroll
    for (int i = 0; i < 64; ++i) {
        row_ptr[base + i] = off;
        count[base + i] = off;   // becomes the scatter cursor
        off += loc[i];
    }
    if (t == 255) row_ptr[N_NODES] = off;   // == N_EDGES
}

__global__ void scatter_kernel(const int* __restrict__ rows, const int* __restrict__ cols,
                               const float* __restrict__ vals,
                               int* __restrict__ cursor,
                               int* __restrict__ csr_col, float* __restrict__ csr_val) {
    int e = blockIdx.x * blockDim.x + threadIdx.x;
    if (e < N_EDGES) {
        int r = rows[e];
        int pos = atomicAdd(&cursor[r], 1);
        csr_col[pos] = cols[e];
        csr_val[pos] = vals[e];
    }
}

// ---------------- Chebyshev step, XCD-chunked: out = c*(L@in - in) - prev ----------------
// chunk = bid&7 -> pinned to one XCD (round-robin dispatch). That XCD only touches
// batch cols [chunk*32, chunk*32+32): a 2 MiB slice that fits its private 4 MiB L2.
// Block: 256 thr = 8 nodes x 32 batch lanes.
__global__ void cheb_kernel(const float* __restrict__ in, const float* __restrict__ prev,
                            float* __restrict__ out,
                            const int* __restrict__ row_ptr,
                            const float* __restrict__ csr_val, const int* __restrict__ csr_col,
                            float c) {
    int chunk = blockIdx.x & (NCHUNK - 1);
    int ng    = blockIdx.x >> 3;
    int nsub  = threadIdx.x >> 5;
    int b     = chunk * CHUNK + (threadIdx.x & 31);
    int n     = ng * NPB + nsub;
    int beg = row_ptr[n], end = row_ptr[n + 1];
    float acc = 0.f;
    int e = beg;
    for (; e + 3 < end; e += 4) {
        int   c0 = csr_col[e],     c1 = csr_col[e + 1], c2 = csr_col[e + 2], c3 = csr_col[e + 3];
        float v0 = csr_val[e],     v1 = csr_val[e + 1], v2 = csr_val[e + 2], v3 = csr_val[e + 3];
        acc += v0 * in[(size_t)c0 * BATCH + b];
        acc += v1 * in[(size_t)c1 * BATCH + b];
        acc += v2 * in[(size_t)c2 * BATCH + b];
        acc += v3 * in[(size_t)c3 * BATCH + b];
    }
    for (; e < end; ++e)
        acc += csr_val[e] * in[(size_t)csr_col[e] * BATCH + b];
    size_t idx = (size_t)n * BATCH + b;
    float o = c * (acc - in[idx]);
    if (prev) o -= prev[idx];
    out[idx] = o;
}

// ---------------- fused final, XCD-chunked ----------------
// Phase 1: 8 nodes x 32 lanes gather (same chunking). Phase 2: per wave, 2 b-values
// x 1KB contiguous (8 nodes x 32 floats) nontemporal stores.
__global__ void final_kernel(const float* __restrict__ t0, const float* __restrict__ t1,
                             const float* __restrict__ t2,
                             const int* __restrict__ row_ptr,
                             const float* __restrict__ csr_val, const int* __restrict__ csr_col,
                             const float* __restrict__ weight, const float* __restrict__ bias,
                             float* __restrict__ out) {
    __shared__ float w[F_OUT * K_ORD];
    __shared__ float bb[F_OUT];
    __shared__ f32x4 tval[NPB][CHUNK];   // [node][b_idx] = {t0,t1,t2,t3}
    int tid = threadIdx.x;
    if (tid < F_OUT * K_ORD) w[tid] = weight[tid];
    if (tid < F_OUT) bb[tid] = bias[tid];

    int chunk = blockIdx.x & (NCHUNK - 1);
    int ng    = blockIdx.x >> 3;
    {
        int nsub = tid >> 5;
        int bi   = tid & 31;
        int b    = chunk * CHUNK + bi;
        int n    = ng * NPB + nsub;
        int beg = row_ptr[n], end = row_ptr[n + 1];
        float acc = 0.f;
        int e = beg;
        for (; e + 3 < end; e += 4) {
            int   c0 = csr_col[e],     c1 = csr_col[e + 1], c2 = csr_col[e + 2], c3 = csr_col[e + 3];
            float v0 = csr_val[e],     v1 = csr_val[e + 1], v2 = csr_val[e + 2], v3 = csr_val[e + 3];
            acc += v0 * t2[(size_t)c0 * BATCH + b];
            acc += v1 * t2[(size_t)c1 * BATCH + b];
            acc += v2 * t2[(size_t)c2 * BATCH + b];
            acc += v3 * t2[(size_t)c3 * BATCH + b];
        }
        for (; e < end; ++e)
            acc += csr_val[e] * t2[(size_t)csr_col[e] * BATCH + b];

        size_t idx = (size_t)n * BATCH + b;
        float t2v = t2[idx];
        float t3v = 2.f * (acc - t2v) - t1[idx];
        tval[nsub][bi] = (f32x4){t0[idx], t1[idx], t2v, t3v};
    }
    __syncthreads();

    // phase 2: 8 nodes x 32 b x 32 f = 2048 f32x4 stores; 8 per thread.
    // thread: f = (tid&7)*4 (const), nsub = (tid>>3)&7 (const), b_idx = i*4 + (tid>>6).
    int f = (tid & 7) * 4;
    f32x4 w0 = *(const f32x4*)&w[(f + 0) * 4];
    f32x4 w1 = *(const f32x4*)&w[(f + 1) * 4];
    f32x4 w2 = *(const f32x4*)&w[(f + 2) * 4];
    f32x4 w3 = *(const f32x4*)&w[(f + 3) * 4];
    f32x4 b4 = *(const f32x4*)&bb[f];

    int nsub = (tid >> 3) & 7;
    int wv   = tid >> 6;
    size_t n = (size_t)(ng * NPB + nsub);
#pragma unroll
    for (int i = 0; i < 8; ++i) {
        int b_idx = i * 4 + wv;                      // 0..31
        size_t b  = (size_t)(chunk * CHUNK + b_idx);
        f32x4 tv = tval[nsub][b_idx];
        f32x4 r;
        r.x = w0.x * tv.x + w0.y * tv.y + w0.z * tv.z + w0.w * tv.w + b4.x;
        r.y = w1.x * tv.x + w1.y * tv.y + w1.z * tv.z + w1.w * tv.w + b4.y;
        r.z = w2.x * tv.x + w2.y * tv.y + w2.z * tv.z + w2.w * tv.w + b4.z;
        r.w = w3.x * tv.x + w3.y * tv.y + w3.z * tv.z + w3.w * tv.w + b4.w;
        __builtin_nontemporal_store(r, (f32x4*)(out + (b * N_NODES + n) * F_OUT + f));
    }
}

extern "C" void kernel_launch(void* const* d_in, const int* in_sizes, int n_in,
                              void* d_out, int out_size, void* d_ws, size_t ws_size,
                              hipStream_t stream) {
    const float* x      = (const float*)d_in[0];
    const float* vals   = (const float*)d_in[1];
    const int*   rows   = (const int*)d_in[2];
    const int*   cols   = (const int*)d_in[3];
    const float* weight = (const float*)d_in[4];
    const float* bias   = (const float*)d_in[5];
    float* out = (float*)d_out;

    const size_t NB = (size_t)N_NODES * BATCH;   // 4,194,304 floats
    float* xT      = (float*)d_ws;
    float* t1      = xT + NB;
    float* t2      = t1 + NB;
    int*   row_ptr = (int*)(t2 + NB);            // N_NODES+1 (pad to 16448)
    int*   cursor  = row_ptr + 16448;            // N_NODES ints; also the histogram
    float* csr_val = (float*)(cursor + N_NODES);
    int*   csr_col = (int*)(csr_val + N_EDGES);

    (void)hipMemsetAsync(cursor, 0, N_NODES * sizeof(int), stream);

    transpose_kernel<<<dim3(N_NODES / 32, BATCH / 32), dim3(32, 8), 0, stream>>>(x, xT);
    hist_kernel<<<N_EDGES / 256, 256, 0, stream>>>(rows, cursor);
    scan_kernel<<<1, 256, 0, stream>>>(cursor, row_ptr);
    scatter_kernel<<<N_EDGES / 256, 256, 0, stream>>>(rows, cols, vals, cursor, csr_col, csr_val);

    const int GRID = (N_NODES / NPB) * NCHUNK;   // 16384 blocks
    cheb_kernel<<<GRID, 256, 0, stream>>>(xT, nullptr, t1, row_ptr, csr_val, csr_col, 1.f);
    cheb_kernel<<<GRID, 256, 0, stream>>>(t1, xT, t2, row_ptr, csr_val, csr_col, 2.f);
    final_kernel<<<GRID, 256, 0, stream>>>(xT, t1, t2, row_ptr, csr_val, csr_col,
                                           weight, bias, out);
}